// Round 1
// baseline (5094.256 us; speedup 1.0000x reference)
//
#include <hip/hip_runtime.h>
#include <hip/hip_bf16.h>

// Problem constants
#define Bz 16
#define Tz 32
#define Sz 128
#define TPz 4
#define Mz (Bz*Sz)          // 2048 rows
#define NSTEP (Tz-1)        // 31

typedef __bf16 bf16x8 __attribute__((ext_vector_type(8)));
typedef float  f32x4  __attribute__((ext_vector_type(4)));

#define MFMA __builtin_amdgcn_mfma_f32_16x16x32_bf16

__device__ __forceinline__ float sigf(float x) { return 1.f/(1.f + __expf(-x)); }

// ---------------------------------------------------------------------------
// Cross-XCD-coherent 16B state load: 2x 8B agent-scope relaxed atomic loads.
// Reads at the coherence point (IC), so consumers never need cache
// invalidation (which would evict the L2-resident weights every step).
// ---------------------------------------------------------------------------
__device__ __forceinline__ bf16x8 ld_state16(const __bf16* p) {
    unsigned long long* q = (unsigned long long*)p;
    unsigned long long lo = __hip_atomic_load(q,     __ATOMIC_RELAXED, __HIP_MEMORY_SCOPE_AGENT);
    unsigned long long hi = __hip_atomic_load(q + 1, __ATOMIC_RELAXED, __HIP_MEMORY_SCOPE_AGENT);
    union { unsigned long long u[2]; bf16x8 v; } x;
    x.u[0] = lo; x.u[1] = hi;
    return x.v;
}

// ---------------------------------------------------------------------------
// prep3 (verified rounds 7/8/10): pack weights (fp32) into bf16 MFMA B-fragment
// order: P[((nt*KT + kt)*64 + lane)*8 + j] =
//        BT[nt*16 + (lane&15)][kt*32 + (lane>>4)*8 + j]
// ---------------------------------------------------------------------------
__global__ __launch_bounds__(256) void prep3(
    const float* __restrict__ encWq, const float* __restrict__ encWk,
    const float* __restrict__ encWv, const float* __restrict__ encWg,
    const float* __restrict__ decWq, const float* __restrict__ decWk,
    const float* __restrict__ decWv, const float* __restrict__ decWg,
    const float* __restrict__ embW,
    __bf16* __restrict__ Pqkv_e, __bf16* __restrict__ Pqkv_d,
    __bf16* __restrict__ Pemb,   __bf16* __restrict__ Pg_e,
    __bf16* __restrict__ Pg_d)
{
    int id = blockIdx.x * 256 + threadIdx.x;
    if (id < 768*256) {
        int f = id >> 9, e = id & 511, l = e >> 3, j = e & 7;
        int nt = f >> 3, kt = f & 7;
        int n = nt*16 + (l & 15), k = kt*32 + (l >> 4)*8 + j;
        float v = (n < 256) ? encWq[k*256 + n]
                : (n < 512) ? encWk[k*256 + (n-256)]
                            : encWv[k*256 + (n-512)];
        Pqkv_e[id] = (__bf16)v; return;
    }
    id -= 768*256;
    if (id < 768*256) {
        int f = id >> 9, e = id & 511, l = e >> 3, j = e & 7;
        int nt = f >> 3, kt = f & 7;
        int n = nt*16 + (l & 15), k = kt*32 + (l >> 4)*8 + j;
        float v = (n < 256) ? decWq[k*256 + n]
                : (n < 512) ? decWk[k*256 + (n-256)]
                            : decWv[k*256 + (n-512)];
        Pqkv_d[id] = (__bf16)v; return;
    }
    id -= 768*256;
    if (id < 256*256) {
        int f = id >> 9, e = id & 511, l = e >> 3, j = e & 7;
        int nt = f >> 3, kt = f & 7;
        int n = nt*16 + (l & 15), k = kt*32 + (l >> 4)*8 + j;
        Pemb[id] = (__bf16)embW[k*256 + n]; return;
    }
    id -= 256*256;
    if (id < 1024*512) {
        int f = id >> 9, e = id & 511, l = e >> 3, j = e & 7;
        int nt = f >> 4, kt = f & 15;
        int cht = nt >> 2, g = nt & 3;
        int ch = cht*16 + (l & 15), k = kt*32 + (l >> 4)*8 + j;
        Pg_e[id] = (__bf16)encWg[(size_t)(3 + k)*1024 + g*256 + ch]; return;
    }
    id -= 1024*512;
    if (id < 1024*768) {
        int f = id >> 9, e = id & 511, l = e >> 3, j = e & 7;
        int nt = f / 24, kt = f % 24;
        int cht = nt >> 2, g = nt & 3;
        int ch = cht*16 + (l & 15), k = kt*32 + (l >> 4)*8 + j;
        Pg_d[id] = (__bf16)decWg[(size_t)k*1024 + g*256 + ch]; return;
    }
}

// ---------------------------------------------------------------------------
// qkv GEMM from 36-row staged state (stride 264) -> qL (own 32 rows), kvL (36).
// (verified rounds 7/8/10)
// ---------------------------------------------------------------------------
__device__ __forceinline__ void qkv_lds(
    const __bf16* src264, const __bf16* __restrict__ P,
    __bf16* qL, __bf16* kvL, int tid)
{
    const int w = tid >> 6, lane = tid & 63, quad = (lane >> 4), lr = lane & 15;
    #pragma unroll
    for (int ng = 0; ng < 3; ++ng) {
        const int ntA = w*6 + ng*2;
        f32x4 acc[2][3];
        #pragma unroll
        for (int i = 0; i < 2; ++i)
            #pragma unroll
            for (int m = 0; m < 3; ++m) acc[i][m] = f32x4{0.f,0.f,0.f,0.f};
        for (int kt = 0; kt < 8; ++kt) {
            bf16x8 a0 = *(const bf16x8*)&src264[(lr)*264      + kt*32 + quad*8];
            bf16x8 a1 = *(const bf16x8*)&src264[(16 + lr)*264 + kt*32 + quad*8];
            bf16x8 a2 = *(const bf16x8*)&src264[(32 + lr)*264 + kt*32 + quad*8];
            bf16x8 b0 = *(const bf16x8*)&P[((size_t)(ntA*8 + kt)*64 + lane)*8];
            bf16x8 b1 = *(const bf16x8*)&P[((size_t)((ntA+1)*8 + kt)*64 + lane)*8];
            acc[0][0] = MFMA(a0, b0, acc[0][0], 0,0,0);
            acc[0][1] = MFMA(a1, b0, acc[0][1], 0,0,0);
            acc[0][2] = MFMA(a2, b0, acc[0][2], 0,0,0);
            acc[1][0] = MFMA(a0, b1, acc[1][0], 0,0,0);
            acc[1][1] = MFMA(a1, b1, acc[1][1], 0,0,0);
            acc[1][2] = MFMA(a2, b1, acc[1][2], 0,0,0);
        }
        #pragma unroll
        for (int i = 0; i < 2; ++i) {
            const int col = (ntA + i)*16 + lr;
            #pragma unroll
            for (int m = 0; m < 3; ++m)
                #pragma unroll
                for (int r = 0; r < 4; ++r) {
                    const int row = m*16 + quad*4 + r;
                    const float v = acc[i][m][r];
                    if (col < 256) {
                        if (row >= 2 && row < 34) qL[(row-2)*264 + col] = (__bf16)v;
                    } else if (row < 36) {
                        kvL[row*520 + (col - 256)] = (__bf16)v;
                    }
                }
        }
    }
}

// ---------------------------------------------------------------------------
// Attention (32 rows) from LDS qL/kvL -> cxL. (verified rounds 7/8/10)
// cxL MAY alias qL: each lane reads only the q chunk it later overwrites.
// ---------------------------------------------------------------------------
__device__ __forceinline__ void attn_lds(
    const __bf16* qL, const __bf16* kvL, __bf16* cxL, int s0, int tid)
{
    const int w = tid >> 6, lane = tid & 63, quad = lane >> 4, lr = lane & 15;
    const int r = 4*w + quad, s = s0 + r, ch0 = lr*16;

    float q[16];
    {
        bf16x8 q0 = *(const bf16x8*)&qL[r*264 + ch0];
        bf16x8 q1 = *(const bf16x8*)&qL[r*264 + ch0 + 8];
        #pragma unroll
        for (int i = 0; i < 8; ++i) { q[i] = (float)q0[i]; q[8+i] = (float)q1[i]; }
    }
    bf16x8 zv;
    #pragma unroll
    for (int i = 0; i < 8; ++i) zv[i] = (__bf16)0.f;

    const int offs[4] = {2, 1, -1, -2};
    float sc[4]; bf16x8 v0[4], v1[4];
    #pragma unroll
    for (int n = 0; n < 4; ++n) {
        const int s2 = s + offs[n];
        const bool ok = ((unsigned)s2 < 128u);
        const int lrow = r + offs[n] + 2;
        float p = 0.f;
        if (ok) {
            bf16x8 k0 = *(const bf16x8*)&kvL[lrow*520 + ch0];
            bf16x8 k1 = *(const bf16x8*)&kvL[lrow*520 + ch0 + 8];
            v0[n] = *(const bf16x8*)&kvL[lrow*520 + 256 + ch0];
            v1[n] = *(const bf16x8*)&kvL[lrow*520 + 256 + ch0 + 8];
            #pragma unroll
            for (int i = 0; i < 8; ++i) p += q[i]*(float)k0[i] + q[8+i]*(float)k1[i];
        } else { v0[n] = zv; v1[n] = zv; }
        p += __shfl_xor(p, 1);
        sc[n] = ok ? p * 0.17677669529663687f : 0.f;
    }
    const float mx = fmaxf(fmaxf(sc[0], sc[1]), fmaxf(sc[2], sc[3]));
    float se = 0.f, aw[4];
    #pragma unroll
    for (int n = 0; n < 4; ++n) { aw[n] = __expf(sc[n] - mx); se += aw[n]; }
    const float inv = 1.f / se;
    float cx[16];
    #pragma unroll
    for (int i = 0; i < 16; ++i) cx[i] = 0.f;
    #pragma unroll
    for (int n = 0; n < 4; ++n)
        #pragma unroll
        for (int i = 0; i < 8; ++i) {
            cx[i]   += aw[n]*(float)v0[n][i];
            cx[8+i] += aw[n]*(float)v1[n][i];
        }
    bf16x8 o0, o1;
    #pragma unroll
    for (int i = 0; i < 8; ++i) { o0[i] = (__bf16)(cx[i]*inv); o1[i] = (__bf16)(cx[8+i]*inv); }
    *(bf16x8*)&cxL[r*264 + ch0]     = o0;
    *(bf16x8*)&cxL[r*264 + ch0 + 8] = o1;
}

// ---------------------------------------------------------------------------
// fused_scan: ONE persistent dispatch for the whole 31-step scan.
//
// blocks 0..255   : dec chain, block (b,rg,qt) runs td = 0..30
// blocks 256..511 : enc chain, block (b,rg,qt) runs k  = 0..30
// Grid == exact residency capacity: 74240B LDS -> 2 blocks/CU, 512 = 2*256,
// __launch_bounds__(512,4) caps VGPR at 128 so both blocks always fit.
//
// Inter-block sync: per-block progress counters (completed-step counts).
//   enc(b,rg,qt)@k  waits: encProg[b,rg-1..rg+1,*] >= k    (RAW eh_{k-1} halo,
//                           + WAR: those neighbors finished reading eh_{k-2})
//                          decProg[b,rg,*]        >= k-1   (WAR: dec read eh_{k-2})
//   dec(b,rg,qt)@td waits: encProg[b,rg,*]        >= td+1  (RAW eh_{td})
//                          decProg[b,rg-1..rg+1,*]>= td    (RAW dh_{td-1} halo +
//                           WAR: neighbors finished reading dh_{td-2})
// All targets strictly precede the waiter in time -> acyclic -> deadlock-free.
// Producers: __syncthreads (drains vmcnt) then agent-scope RELEASE store
// (L2 writeback -> coherence point). Consumers: relaxed spin on the flag,
// then all cross-block state is read with agent-scope atomic loads
// (ld_state16) straight from the coherence point -> no cache invalidation,
// weights stay L2-resident for the whole scan.
// State writes are 128B-line-aligned per block slice (qt*64 bf16 chans =
// 128B), so no cache line is shared RW across XCDs.
// Per-step math is verbatim from the verified step_k -> identical fp order.
// ---------------------------------------------------------------------------
#define SM_A264   0
#define SM_R      19008
#define SM_CODE   35904
#define SM_Q      56448
#define SM_MISC   73344
#define SM_TOTAL  73856

__global__ __launch_bounds__(512, 4) void fused_scan(
    const float* __restrict__ input,
    __bf16* __restrict__ Xa, __bf16* __restrict__ Xb,
    const __bf16* __restrict__ Pqkv_e, const __bf16* __restrict__ Pqkv_d,
    const __bf16* __restrict__ Pemb,   const __bf16* __restrict__ Pg_e,
    const __bf16* __restrict__ Pg_d,
    const float* __restrict__ encWg, const float* __restrict__ encbg,
    const float* __restrict__ decbg, const float* __restrict__ embb,
    const float* __restrict__ outW,
    float* __restrict__ ec, float* __restrict__ outbuf,
    int* __restrict__ encProg, int* __restrict__ decProg)
{
    __shared__ __attribute__((aligned(16))) char SM[SM_TOTAL];

    const int tid  = threadIdx.x;
    const int w    = tid >> 6;
    const int lane = tid & 63;
    const int quad = lane >> 4, lr = lane & 15;
    const int mt = w >> 2, ct = w & 3;

    const bool isEnc = (blockIdx.x >= 256);
    const int bid = isEnc ? ((int)blockIdx.x - 256) : (int)blockIdx.x;
    const int b = bid >> 4, rg = (bid >> 2) & 3, qt = bid & 3;
    const int gbatch = b*128, s0 = rg*32, grow0 = gbatch + s0;
    const int ch = qt*64 + ct*16 + lr;

    __bf16* aL  = (__bf16*)(SM + SM_A264);   // hL / dhL
    __bf16* kvL = (__bf16*)(SM + SM_R);
    __bf16* qL  = (__bf16*)(SM + SM_Q);
    __bf16* cxL = qL;                        // alias (safe, see attn_lds)

    // ---- static producer assignment for spin lanes (tid 0..15) ----
    int* prodPtr = nullptr; int off = 0;
    if (isEnc) {
        if (tid < 12) {
            const int rr = rg - 1 + (tid >> 2), qq = tid & 3;
            if (rr >= 0 && rr < 4) { prodPtr = &encProg[b*16 + rr*4 + qq]; off = 0; }
        } else if (tid < 16) {
            prodPtr = &decProg[b*16 + rg*4 + (tid - 12)]; off = -1;
        }
    } else {
        if (tid < 4) {
            prodPtr = &encProg[b*16 + rg*4 + tid]; off = 1;
        } else if (tid < 16) {
            const int j = tid - 4;
            const int rr = rg - 1 + (j >> 2), qq = j & 3;
            if (rr >= 0 && rr < 4) { prodPtr = &decProg[b*16 + rr*4 + qq]; off = 0; }
        }
    }
    int* myFlag = isEnc ? &encProg[bid] : &decProg[bid];

    for (int step = 0; step < NSTEP; ++step) {
        // ---- wait on producers (lanes 0..15 of wave 0; divergent spin) ----
        if (prodPtr) {
            const int target = step + off;
            if (target > 0) {
                int guard = 0;
                while (__hip_atomic_load(prodPtr, __ATOMIC_RELAXED,
                                         __HIP_MEMORY_SCOPE_AGENT) < target) {
                    __builtin_amdgcn_s_sleep(2);
                    if (++guard > (1 << 20)) break;   // never hang: fail visibly
                }
            }
        }
        asm volatile("" ::: "memory");
        __syncthreads();   // gates all waves' state reads behind the spin;
                           // also protects LDS reuse across iterations

        const int kd = isEnc ? step : (step + 1);    // dispatch-index semantics
        __bf16* P = (kd & 1) ? Xb : Xa;
        __bf16* Q = (kd & 1) ? Xa : Xb;

        if (isEnc) {
            // ===================== ENC body (step k = step) =====================
            const int k = step;
            float* xL = (float*)(SM + SM_MISC);

            // stage eh_{k-1} halo rows (s0-2 .. s0+33) from P.enc (cross-block)
            for (int v = tid; v < 36*32; v += 512) {
                const int row = v >> 5, seg = v & 31, s = s0 - 2 + row;
                bf16x8 val;
                if ((unsigned)s < 128u)
                    val = ld_state16(&P[(size_t)(gbatch + s)*512 + seg*8]);
                else {
                    #pragma unroll
                    for (int i = 0; i < 8; ++i) val[i] = (__bf16)0.f;
                }
                *(bf16x8*)&aL[row*264 + seg*8] = val;
            }
            if (tid < 96) xL[tid] = input[((size_t)(b*Tz + k)*Sz + s0)*3 + tid];
            __syncthreads();

            qkv_lds(aL, Pqkv_e, qL, kvL, tid);
            __syncthreads();
            attn_lds(qL, kvL, cxL, s0, tid);
            __syncthreads();

            // gates (K=512: aL own rows | cxL) + LSTM
            float wx0[4], wx1[4], wx2[4], bgv[4];
            #pragma unroll
            for (int g = 0; g < 4; ++g) {
                const int c = g*256 + ch;
                wx0[g] = encWg[c]; wx1[g] = encWg[1024 + c]; wx2[g] = encWg[2048 + c];
                bgv[g] = encbg[c];
            }
            f32x4 acc[4];
            #pragma unroll
            for (int g = 0; g < 4; ++g) acc[g] = f32x4{0.f,0.f,0.f,0.f};
            for (int kt = 0; kt < 16; ++kt) {
                const __bf16* As = (kt < 8)
                    ? &aL [(2 + mt*16 + lr)*264 + kt*32 + quad*8]
                    : &cxL[(mt*16 + lr)*264 + (kt-8)*32 + quad*8];
                bf16x8 af = *(const bf16x8*)As;
                #pragma unroll
                for (int g = 0; g < 4; ++g) {
                    const int nt = qt*16 + ct*4 + g;
                    bf16x8 bf = *(const bf16x8*)&Pg_e[((size_t)(nt*16 + kt)*64 + lane)*8];
                    acc[g] = MFMA(af, bf, acc[g], 0,0,0);
                }
            }
            #pragma unroll
            for (int r = 0; r < 4; ++r) {
                const int row = mt*16 + quad*4 + r;
                const float x0 = xL[row*3], x1 = xL[row*3+1], x2 = xL[row*3+2];
                const float zi = acc[0][r] + x0*wx0[0] + x1*wx1[0] + x2*wx2[0] + bgv[0];
                const float zf = acc[1][r] + x0*wx0[1] + x1*wx1[1] + x2*wx2[1] + bgv[1];
                const float zg = acc[2][r] + x0*wx0[2] + x1*wx1[2] + x2*wx2[2] + bgv[2];
                const float zo = acc[3][r] + x0*wx0[3] + x1*wx1[3] + x2*wx2[3] + bgv[3];
                const size_t ei = (size_t)(grow0 + row)*256 + ch;
                const float cn = sigf(zf)*ec[ei] + sigf(zi)*tanhf(zg);
                ec[ei] = cn;
                Q[(size_t)(grow0 + row)*512 + ch] = (__bf16)(sigf(zo)*tanhf(cn));
            }
        } else {
            // ===================== DEC body (step td = step) =====================
            const int td = step;
            __bf16* dhL   = aL;
            __bf16* ehtL  = (__bf16*)(SM + SM_R);      // dead after code GEMM
            __bf16* codeL = (__bf16*)(SM + SM_CODE);   // dead after gates code-part
            float* outredL = (float*)(SM + SM_MISC);

            // stage eh_{td} own rows (P.enc) + dh_{td-1} halo (Q.dh) (cross-block)
            for (int v = tid; v < 32*32; v += 512) {
                const int row = v >> 5, seg = v & 31;
                *(bf16x8*)&ehtL[row*264 + seg*8] =
                    ld_state16(&P[(size_t)(grow0 + row)*512 + seg*8]);
            }
            for (int v = tid; v < 36*32; v += 512) {
                const int row = v >> 5, seg = v & 31, s = s0 - 2 + row;
                bf16x8 val;
                if ((unsigned)s < 128u)
                    val = ld_state16(&Q[(size_t)(gbatch + s)*512 + 256 + seg*8]);
                else {
                    #pragma unroll
                    for (int i = 0; i < 8; ++i) val[i] = (__bf16)0.f;
                }
                *(bf16x8*)&dhL[row*264 + seg*8] = val;
            }
            __syncthreads();

            // code = sig(eh_{td} @ embW + embb) -> codeL
            {
                f32x4 cacc[2][2];
                #pragma unroll
                for (int m = 0; m < 2; ++m)
                    #pragma unroll
                    for (int i = 0; i < 2; ++i) cacc[m][i] = f32x4{0.f,0.f,0.f,0.f};
                for (int kt = 0; kt < 8; ++kt) {
                    bf16x8 a0 = *(const bf16x8*)&ehtL[(lr)*264      + kt*32 + quad*8];
                    bf16x8 a1 = *(const bf16x8*)&ehtL[(16 + lr)*264 + kt*32 + quad*8];
                    #pragma unroll
                    for (int i = 0; i < 2; ++i) {
                        bf16x8 bf = *(const bf16x8*)&Pemb[((size_t)((2*w + i)*8 + kt)*64 + lane)*8];
                        cacc[0][i] = MFMA(a0, bf, cacc[0][i], 0,0,0);
                        cacc[1][i] = MFMA(a1, bf, cacc[1][i], 0,0,0);
                    }
                }
                __syncthreads();   // all ehtL reads done before codeL writes
                #pragma unroll
                for (int i = 0; i < 2; ++i) {
                    const int col = (2*w + i)*16 + lr;
                    const float bb = embb[col];
                    #pragma unroll
                    for (int m = 0; m < 2; ++m)
                        #pragma unroll
                        for (int r = 0; r < 4; ++r)
                            codeL[(m*16 + quad*4 + r)*264 + col] = (__bf16)sigf(cacc[m][i][r] + bb);
                }
            }
            __syncthreads();

            // gates acc: code part FIRST (kt 0..7) so codeL dies before kvL overlay
            float bgv[4];
            #pragma unroll
            for (int g = 0; g < 4; ++g) bgv[g] = decbg[g*256 + ch];
            const float ow = outW[ch];

            f32x4 acc[4];
            #pragma unroll
            for (int g = 0; g < 4; ++g) acc[g] = f32x4{0.f,0.f,0.f,0.f};
            for (int kt = 0; kt < 8; ++kt) {
                bf16x8 af = *(const bf16x8*)&codeL[(mt*16 + lr)*264 + kt*32 + quad*8];
                #pragma unroll
                for (int g = 0; g < 4; ++g) {
                    const int nt = qt*16 + ct*4 + g;
                    bf16x8 bf = *(const bf16x8*)&Pg_d[((size_t)(nt*24 + kt)*64 + lane)*8];
                    acc[g] = MFMA(af, bf, acc[g], 0,0,0);
                }
            }
            __syncthreads();   // codeL/ehtL dead; kvL may now overwrite region R

            // dec qkv from dh_{td-1} halo (kvL overlays ehtL+codeL region)
            qkv_lds(dhL, Pqkv_d, qL, kvL, tid);
            __syncthreads();
            attn_lds(qL, kvL, cxL, s0, tid);
            __syncthreads();

            // gates rest (kt 8..23: dhL own | cxL) + LSTM + outproj
            for (int kt = 8; kt < 24; ++kt) {
                const __bf16* As = (kt < 16)
                    ? &dhL[(2 + mt*16 + lr)*264 + (kt-8)*32 + quad*8]
                    : &cxL[(mt*16 + lr)*264 + (kt-16)*32 + quad*8];
                bf16x8 af = *(const bf16x8*)As;
                #pragma unroll
                for (int g = 0; g < 4; ++g) {
                    const int nt = qt*16 + ct*4 + g;
                    bf16x8 bf = *(const bf16x8*)&Pg_d[((size_t)(nt*24 + kt)*64 + lane)*8];
                    acc[g] = MFMA(af, bf, acc[g], 0,0,0);
                }
            }
            #pragma unroll
            for (int r = 0; r < 4; ++r) {
                const int row = mt*16 + quad*4 + r;
                const float zi = acc[0][r] + bgv[0];
                const float zf = acc[1][r] + bgv[1];
                const float zg = acc[2][r] + bgv[2];
                const float zo = acc[3][r] + bgv[3];
                const float c_old = (float)dhL[(2 + row)*264 + ch];
                const float cn = sigf(zf)*c_old + sigf(zi)*tanhf(zg);
                const float h  = sigf(zo)*tanhf(cn);
                P[(size_t)(grow0 + row)*512 + 256 + ch] = (__bf16)h;
                float pv = h * ow;
                pv += __shfl_xor(pv, 1); pv += __shfl_xor(pv, 2);
                pv += __shfl_xor(pv, 4); pv += __shfl_xor(pv, 8);
                if (lr == 0) outredL[row*4 + ct] = pv;
            }
            __syncthreads();
            if (tid < 32) {
                const float s4 = outredL[tid*4] + outredL[tid*4+1]
                               + outredL[tid*4+2] + outredL[tid*4+3];
                atomicAdd(&outbuf[(size_t)td*Mz + grow0 + tid], s4);
            }
        }

        // ---- publish: barrier drains all waves' writes to L2 (vmcnt(0)),
        //      release store writes L2 back to the coherence point ----
        __syncthreads();
        if (tid == 0)
            __hip_atomic_store(myFlag, step + 1, __ATOMIC_RELEASE,
                               __HIP_MEMORY_SCOPE_AGENT);
    }
}

// ---------------------------------------------------------------------------
// Final assembly (unchanged, verified)
// ---------------------------------------------------------------------------
__global__ __launch_bounds__(256) void assemble_k(
    const float* __restrict__ outbuf, const float* __restrict__ input,
    const float* __restrict__ outb, float* __restrict__ out)
{
    const int idx = blockIdx.x*256 + threadIdx.x;
    const int NT = NSTEP - TPz;                 // 27
    if (idx >= Bz*NT*Sz) return;
    const int s  = idx & 127;
    const int bi = idx >> 7;
    const int i  = bi % NT;
    const int b  = bi / NT;
    const int t  = i + TPz;
    const float ob = outb[0];
    const float o  = outbuf[t*Mz + (b<<7) + s] + ob;
    const float In = (s == 0)
        ? input[((size_t)(b*Tz + t + 1)*Sz)*3 + 1]
        : outbuf[t*Mz + (b<<7) + s - 1] + ob;
    const float num = input[((size_t)(b*Tz + t)*Sz + s)*3 + 2] + In - o;
    const size_t base = ((size_t)(b*NT + i)*Sz + s)*3;
    out[base+0] = o;
    out[base+1] = In;
    out[base+2] = num;
}

// ---------------------------------------------------------------------------
extern "C" void kernel_launch(void* const* d_in, const int* in_sizes, int n_in,
                              void* d_out, int out_size, void* d_ws, size_t ws_size,
                              hipStream_t stream)
{
    const float* input = (const float*)d_in[0];
    const float* encWq = (const float*)d_in[1];
    const float* encWk = (const float*)d_in[2];
    const float* encWv = (const float*)d_in[3];
    const float* encWg = (const float*)d_in[4];
    const float* encbg = (const float*)d_in[5];
    const float* decWq = (const float*)d_in[6];
    const float* decWk = (const float*)d_in[7];
    const float* decWv = (const float*)d_in[8];
    const float* decWg = (const float*)d_in[9];
    const float* decbg = (const float*)d_in[10];
    const float* embW  = (const float*)d_in[11];
    const float* embb  = (const float*)d_in[12];
    const float* outW  = (const float*)d_in[13];
    const float* outb  = (const float*)d_in[14];

    char* ws = (char*)d_ws;
    size_t off = 0;
    auto alloc = [&](size_t bytes) -> void* {
        void* p = ws + off;
        off += (bytes + 255) & ~(size_t)255;
        return p;
    };
    __bf16* Pqkv_e = (__bf16*)alloc((size_t)768*256*2);
    __bf16* Pqkv_d = (__bf16*)alloc((size_t)768*256*2);
    __bf16* Pemb   = (__bf16*)alloc((size_t)256*256*2);
    __bf16* Pg_e   = (__bf16*)alloc((size_t)1024*512*2);
    __bf16* Pg_d   = (__bf16*)alloc((size_t)1024*768*2);
    __bf16* Xa     = (__bf16*)alloc((size_t)Mz*512*2);   // [ehb|dh] ping
    __bf16* Xb     = (__bf16*)alloc((size_t)Mz*512*2);   // pong
    float*  ec     = (float*) alloc((size_t)Mz*256*4);
    float*  outbuf = (float*) alloc((size_t)NSTEP*Mz*4);
    int*    prog   = (int*)   alloc((size_t)512*4);      // [dec 256 | enc 256]

    hipMemsetAsync(Xa, 0, (size_t)Mz*512*2, stream);
    hipMemsetAsync(ec, 0, (size_t)Mz*256*4, stream);
    hipMemsetAsync(outbuf, 0, (size_t)NSTEP*Mz*4, stream);
    hipMemsetAsync(prog, 0, (size_t)512*4, stream);

    prep3<<<6912, 256, 0, stream>>>(encWq, encWk, encWv, encWg,
                                    decWq, decWk, decWv, decWg, embW,
                                    Pqkv_e, Pqkv_d, Pemb, Pg_e, Pg_d);

    fused_scan<<<512, 512, 0, stream>>>(input, Xa, Xb,
                                        Pqkv_e, Pqkv_d, Pemb, Pg_e, Pg_d,
                                        encWg, encbg, decbg, embb, outW,
                                        ec, outbuf,
                                        /*encProg=*/prog + 256,
                                        /*decProg=*/prog);

    assemble_k<<<(Bz*(NSTEP-TPz)*Sz + 255)/256, 256, 0, stream>>>(
        outbuf, input, outb, (float*)d_out);
}

// Round 2
// 1356.833 us; speedup vs baseline: 3.7545x; 3.7545x over previous
//
#include <hip/hip_runtime.h>
#include <hip/hip_bf16.h>

// Problem constants
#define Bz 16
#define Tz 32
#define Sz 128
#define TPz 4
#define Mz (Bz*Sz)          // 2048 rows
#define NSTEP (Tz-1)        // 31

typedef __bf16 bf16x8 __attribute__((ext_vector_type(8)));
typedef float  f32x4  __attribute__((ext_vector_type(4)));

#define MFMA __builtin_amdgcn_mfma_f32_16x16x32_bf16

__device__ __forceinline__ float sigf(float x) { return 1.f/(1.f + __expf(-x)); }

// ---------------------------------------------------------------------------
// prep3 (verified rounds 7/8/10): pack weights (fp32) into bf16 MFMA B-fragment
// order: P[((nt*KT + kt)*64 + lane)*8 + j] =
//        BT[nt*16 + (lane&15)][kt*32 + (lane>>4)*8 + j]
// ---------------------------------------------------------------------------
__global__ __launch_bounds__(256) void prep3(
    const float* __restrict__ encWq, const float* __restrict__ encWk,
    const float* __restrict__ encWv, const float* __restrict__ encWg,
    const float* __restrict__ decWq, const float* __restrict__ decWk,
    const float* __restrict__ decWv, const float* __restrict__ decWg,
    const float* __restrict__ embW,
    __bf16* __restrict__ Pqkv_e, __bf16* __restrict__ Pqkv_d,
    __bf16* __restrict__ Pemb,   __bf16* __restrict__ Pg_e,
    __bf16* __restrict__ Pg_d)
{
    int id = blockIdx.x * 256 + threadIdx.x;
    if (id < 768*256) {
        int f = id >> 9, e = id & 511, l = e >> 3, j = e & 7;
        int nt = f >> 3, kt = f & 7;
        int n = nt*16 + (l & 15), k = kt*32 + (l >> 4)*8 + j;
        float v = (n < 256) ? encWq[k*256 + n]
                : (n < 512) ? encWk[k*256 + (n-256)]
                            : encWv[k*256 + (n-512)];
        Pqkv_e[id] = (__bf16)v; return;
    }
    id -= 768*256;
    if (id < 768*256) {
        int f = id >> 9, e = id & 511, l = e >> 3, j = e & 7;
        int nt = f >> 3, kt = f & 7;
        int n = nt*16 + (l & 15), k = kt*32 + (l >> 4)*8 + j;
        float v = (n < 256) ? decWq[k*256 + n]
                : (n < 512) ? decWk[k*256 + (n-256)]
                            : decWv[k*256 + (n-512)];
        Pqkv_d[id] = (__bf16)v; return;
    }
    id -= 768*256;
    if (id < 256*256) {
        int f = id >> 9, e = id & 511, l = e >> 3, j = e & 7;
        int nt = f >> 3, kt = f & 7;
        int n = nt*16 + (l & 15), k = kt*32 + (l >> 4)*8 + j;
        Pemb[id] = (__bf16)embW[k*256 + n]; return;
    }
    id -= 256*256;
    if (id < 1024*512) {
        int f = id >> 9, e = id & 511, l = e >> 3, j = e & 7;
        int nt = f >> 4, kt = f & 15;
        int cht = nt >> 2, g = nt & 3;
        int ch = cht*16 + (l & 15), k = kt*32 + (l >> 4)*8 + j;
        Pg_e[id] = (__bf16)encWg[(size_t)(3 + k)*1024 + g*256 + ch]; return;
    }
    id -= 1024*512;
    if (id < 1024*768) {
        int f = id >> 9, e = id & 511, l = e >> 3, j = e & 7;
        int nt = f / 24, kt = f % 24;
        int cht = nt >> 2, g = nt & 3;
        int ch = cht*16 + (l & 15), k = kt*32 + (l >> 4)*8 + j;
        Pg_d[id] = (__bf16)decWg[(size_t)k*1024 + g*256 + ch]; return;
    }
}

// ---------------------------------------------------------------------------
// qkv GEMM from 36-row staged state (stride 264) -> qL (own 32 rows), kvL (36).
// (verified rounds 7/8/10)
// ---------------------------------------------------------------------------
__device__ __forceinline__ void qkv_lds(
    const __bf16* src264, const __bf16* __restrict__ P,
    __bf16* qL, __bf16* kvL, int tid)
{
    const int w = tid >> 6, lane = tid & 63, quad = (lane >> 4), lr = lane & 15;
    #pragma unroll
    for (int ng = 0; ng < 3; ++ng) {
        const int ntA = w*6 + ng*2;
        f32x4 acc[2][3];
        #pragma unroll
        for (int i = 0; i < 2; ++i)
            #pragma unroll
            for (int m = 0; m < 3; ++m) acc[i][m] = f32x4{0.f,0.f,0.f,0.f};
        for (int kt = 0; kt < 8; ++kt) {
            bf16x8 a0 = *(const bf16x8*)&src264[(lr)*264      + kt*32 + quad*8];
            bf16x8 a1 = *(const bf16x8*)&src264[(16 + lr)*264 + kt*32 + quad*8];
            bf16x8 a2 = *(const bf16x8*)&src264[(32 + lr)*264 + kt*32 + quad*8];
            bf16x8 b0 = *(const bf16x8*)&P[((size_t)(ntA*8 + kt)*64 + lane)*8];
            bf16x8 b1 = *(const bf16x8*)&P[((size_t)((ntA+1)*8 + kt)*64 + lane)*8];
            acc[0][0] = MFMA(a0, b0, acc[0][0], 0,0,0);
            acc[0][1] = MFMA(a1, b0, acc[0][1], 0,0,0);
            acc[0][2] = MFMA(a2, b0, acc[0][2], 0,0,0);
            acc[1][0] = MFMA(a0, b1, acc[1][0], 0,0,0);
            acc[1][1] = MFMA(a1, b1, acc[1][1], 0,0,0);
            acc[1][2] = MFMA(a2, b1, acc[1][2], 0,0,0);
        }
        #pragma unroll
        for (int i = 0; i < 2; ++i) {
            const int col = (ntA + i)*16 + lr;
            #pragma unroll
            for (int m = 0; m < 3; ++m)
                #pragma unroll
                for (int r = 0; r < 4; ++r) {
                    const int row = m*16 + quad*4 + r;
                    const float v = acc[i][m][r];
                    if (col < 256) {
                        if (row >= 2 && row < 34) qL[(row-2)*264 + col] = (__bf16)v;
                    } else if (row < 36) {
                        kvL[row*520 + (col - 256)] = (__bf16)v;
                    }
                }
        }
    }
}

// ---------------------------------------------------------------------------
// Attention (32 rows) from LDS qL/kvL -> cxL. (verified rounds 7/8/10)
// cxL MAY alias qL: each lane reads only the q chunk it later overwrites.
// ---------------------------------------------------------------------------
__device__ __forceinline__ void attn_lds(
    const __bf16* qL, const __bf16* kvL, __bf16* cxL, int s0, int tid)
{
    const int w = tid >> 6, lane = tid & 63, quad = lane >> 4, lr = lane & 15;
    const int r = 4*w + quad, s = s0 + r, ch0 = lr*16;

    float q[16];
    {
        bf16x8 q0 = *(const bf16x8*)&qL[r*264 + ch0];
        bf16x8 q1 = *(const bf16x8*)&qL[r*264 + ch0 + 8];
        #pragma unroll
        for (int i = 0; i < 8; ++i) { q[i] = (float)q0[i]; q[8+i] = (float)q1[i]; }
    }
    bf16x8 zv;
    #pragma unroll
    for (int i = 0; i < 8; ++i) zv[i] = (__bf16)0.f;

    const int offs[4] = {2, 1, -1, -2};
    float sc[4]; bf16x8 v0[4], v1[4];
    #pragma unroll
    for (int n = 0; n < 4; ++n) {
        const int s2 = s + offs[n];
        const bool ok = ((unsigned)s2 < 128u);
        const int lrow = r + offs[n] + 2;
        float p = 0.f;
        if (ok) {
            bf16x8 k0 = *(const bf16x8*)&kvL[lrow*520 + ch0];
            bf16x8 k1 = *(const bf16x8*)&kvL[lrow*520 + ch0 + 8];
            v0[n] = *(const bf16x8*)&kvL[lrow*520 + 256 + ch0];
            v1[n] = *(const bf16x8*)&kvL[lrow*520 + 256 + ch0 + 8];
            #pragma unroll
            for (int i = 0; i < 8; ++i) p += q[i]*(float)k0[i] + q[8+i]*(float)k1[i];
        } else { v0[n] = zv; v1[n] = zv; }
        p += __shfl_xor(p, 1);
        sc[n] = ok ? p * 0.17677669529663687f : 0.f;
    }
    const float mx = fmaxf(fmaxf(sc[0], sc[1]), fmaxf(sc[2], sc[3]));
    float se = 0.f, aw[4];
    #pragma unroll
    for (int n = 0; n < 4; ++n) { aw[n] = __expf(sc[n] - mx); se += aw[n]; }
    const float inv = 1.f / se;
    float cx[16];
    #pragma unroll
    for (int i = 0; i < 16; ++i) cx[i] = 0.f;
    #pragma unroll
    for (int n = 0; n < 4; ++n)
        #pragma unroll
        for (int i = 0; i < 8; ++i) {
            cx[i]   += aw[n]*(float)v0[n][i];
            cx[8+i] += aw[n]*(float)v1[n][i];
        }
    bf16x8 o0, o1;
    #pragma unroll
    for (int i = 0; i < 8; ++i) { o0[i] = (__bf16)(cx[i]*inv); o1[i] = (__bf16)(cx[8+i]*inv); }
    *(bf16x8*)&cxL[r*264 + ch0]     = o0;
    *(bf16x8*)&cxL[r*264 + ch0 + 8] = o1;
}

// ---------------------------------------------------------------------------
// step_k: ONE dispatch per scan step k (k = 0..NSTEP).
// blocks 0..255  : dec step td = k-1 (skip if k==0)
// blocks 256..511: enc step te = k   (skip if k==NSTEP)
//
// NEW (this round): L2 warm-up prefetch. Dispatch start invalidates L2, so the
// ~3.4 MB of packed weight fragments are otherwise fetched from IC on demand
// at 16B granularity inside the MFMA loops (latency-exposed, ~600cy each,
// only 16 waves/CU to hide it -> the step trickles its 17 MB over 40 us at
// 730 GB/s). Each block prefetches a 1/32 slice of its type's weight set
// (one dword per 64B line, issued before staging, dead-use kept alive via
// asm). Blocks sharing an XCD (blockIdx.x & 7 under round-robin dispatch)
// cover the full set cooperatively -> weights stream into L2 at full MLP
// concurrently with state staging; MFMA loops then run from warm L2.
// Enc blocks additionally prefetch their ec slice (read at the end of a
// long dependent chain). No math changes.
// ---------------------------------------------------------------------------
#define SM_A264   0
#define SM_R      19008
#define SM_CODE   35904
#define SM_Q      56448
#define SM_MISC   73344
#define SM_TOTAL  73856

__global__ __launch_bounds__(512, 4) void step_k(
    int k, const float* __restrict__ input,
    __bf16* __restrict__ P, __bf16* __restrict__ Q,
    const __bf16* __restrict__ Pqkv_e, const __bf16* __restrict__ Pqkv_d,
    const __bf16* __restrict__ Pemb,   const __bf16* __restrict__ Pg_e,
    const __bf16* __restrict__ Pg_d,
    const float* __restrict__ encWg, const float* __restrict__ encbg,
    const float* __restrict__ decbg, const float* __restrict__ embb,
    const float* __restrict__ outW,
    float* __restrict__ ec, float* __restrict__ outbuf)
{
    __shared__ __attribute__((aligned(16))) char SM[SM_TOTAL];

    const int tid  = threadIdx.x;
    const int w    = tid >> 6;
    const int lane = tid & 63;
    const int quad = lane >> 4, lr = lane & 15;
    const int mt = w >> 2, ct = w & 3;

    __bf16* aL  = (__bf16*)(SM + SM_A264);   // hL / dhL
    __bf16* kvL = (__bf16*)(SM + SM_R);
    __bf16* qL  = (__bf16*)(SM + SM_Q);
    __bf16* cxL = qL;                        // alias (safe, see attn_lds)

    if (blockIdx.x >= 256) {
        // ===================== ENC body (step te = k) =====================
        if (k >= NSTEP) return;
        const int bid = blockIdx.x - 256;
        const int b = bid >> 4, rg = (bid >> 2) & 3, qt = bid & 3;
        const int gbatch = b*128, s0 = rg*32, grow0 = gbatch + s0;
        const int ch = qt*64 + ct*16 + lr;
        float* xL = (float*)(SM + SM_MISC);

        // ---- L2 warm-up prefetch: slice of [Pqkv_e | Pg_e] + own ec ----
        // enc set = 393216 + 1048576 = 1441792 B = 22528 lines; 704/slice.
        float pref = 0.f;
        {
            const int slice = bid >> 3;          // 0..31 (XCD-mates differ)
            const int base = slice * 704;
            for (int i = base + tid; i < base + 704; i += 512) {
                const size_t off = (size_t)i * 64;
                const char* p = (off < 393216)
                    ? (const char*)Pqkv_e + off
                    : (const char*)Pg_e + (off - 393216);
                pref += *(const volatile float*)p;
            }
            for (int i = tid; i < 128; i += 512) {   // ec: 32 rows x 256B
                const int row = i >> 2, part = i & 3;
                pref += *(const volatile float*)
                    &ec[(size_t)(grow0 + row)*256 + qt*64 + part*16];
            }
        }

        // stage eh_{k-1} halo rows (s0-2 .. s0+33) from P.enc
        for (int v = tid; v < 36*32; v += 512) {
            const int row = v >> 5, seg = v & 31, s = s0 - 2 + row;
            bf16x8 val;
            if ((unsigned)s < 128u)
                val = *(const bf16x8*)&P[(size_t)(gbatch + s)*512 + seg*8];
            else {
                #pragma unroll
                for (int i = 0; i < 8; ++i) val[i] = (__bf16)0.f;
            }
            *(bf16x8*)&aL[row*264 + seg*8] = val;
        }
        if (tid < 96) xL[tid] = input[((size_t)(b*Tz + k)*Sz + s0)*3 + tid];
        asm volatile("" :: "v"(pref));   // keep prefetch loads alive
        __syncthreads();

        qkv_lds(aL, Pqkv_e, qL, kvL, tid);
        __syncthreads();
        attn_lds(qL, kvL, cxL, s0, tid);
        __syncthreads();

        // gates (K=512: aL own rows | cxL) + LSTM
        float wx0[4], wx1[4], wx2[4], bgv[4];
        #pragma unroll
        for (int g = 0; g < 4; ++g) {
            const int c = g*256 + ch;
            wx0[g] = encWg[c]; wx1[g] = encWg[1024 + c]; wx2[g] = encWg[2048 + c];
            bgv[g] = encbg[c];
        }
        f32x4 acc[4];
        #pragma unroll
        for (int g = 0; g < 4; ++g) acc[g] = f32x4{0.f,0.f,0.f,0.f};
        for (int kt = 0; kt < 16; ++kt) {
            const __bf16* As = (kt < 8)
                ? &aL [(2 + mt*16 + lr)*264 + kt*32 + quad*8]
                : &cxL[(mt*16 + lr)*264 + (kt-8)*32 + quad*8];
            bf16x8 af = *(const bf16x8*)As;
            #pragma unroll
            for (int g = 0; g < 4; ++g) {
                const int nt = qt*16 + ct*4 + g;
                bf16x8 bf = *(const bf16x8*)&Pg_e[((size_t)(nt*16 + kt)*64 + lane)*8];
                acc[g] = MFMA(af, bf, acc[g], 0,0,0);
            }
        }
        #pragma unroll
        for (int r = 0; r < 4; ++r) {
            const int row = mt*16 + quad*4 + r;
            const float x0 = xL[row*3], x1 = xL[row*3+1], x2 = xL[row*3+2];
            const float zi = acc[0][r] + x0*wx0[0] + x1*wx1[0] + x2*wx2[0] + bgv[0];
            const float zf = acc[1][r] + x0*wx0[1] + x1*wx1[1] + x2*wx2[1] + bgv[1];
            const float zg = acc[2][r] + x0*wx0[2] + x1*wx1[2] + x2*wx2[2] + bgv[2];
            const float zo = acc[3][r] + x0*wx0[3] + x1*wx1[3] + x2*wx2[3] + bgv[3];
            const size_t ei = (size_t)(grow0 + row)*256 + ch;
            const float cn = sigf(zf)*ec[ei] + sigf(zi)*tanhf(zg);
            ec[ei] = cn;
            Q[(size_t)(grow0 + row)*512 + ch] = (__bf16)(sigf(zo)*tanhf(cn));
        }
    } else {
        // ===================== DEC body (step td = k-1) =====================
        if (k < 1) return;
        const int td = k - 1;
        const int bid = blockIdx.x;
        const int b = bid >> 4, rg = (bid >> 2) & 3, qt = bid & 3;
        const int gbatch = b*128, s0 = rg*32, grow0 = gbatch + s0;
        const int ch = qt*64 + ct*16 + lr;
        __bf16* dhL   = aL;
        __bf16* ehtL  = (__bf16*)(SM + SM_R);      // dead after code GEMM
        __bf16* codeL = (__bf16*)(SM + SM_CODE);   // dead after gates code-part
        float* outredL = (float*)(SM + SM_MISC);

        // ---- L2 warm-up prefetch: slice of [Pqkv_d | Pemb | Pg_d] ----
        // dec set = 393216 + 131072 + 1572864 = 2097152 B = 32768 lines; 1024/slice.
        float pref = 0.f;
        {
            const int slice = bid >> 3;          // 0..31 (XCD-mates differ)
            const int base = slice * 1024;
            for (int i = base + tid; i < base + 1024; i += 512) {
                const size_t off = (size_t)i * 64;
                const char* p;
                if (off < 393216)       p = (const char*)Pqkv_d + off;
                else if (off < 524288)  p = (const char*)Pemb + (off - 393216);
                else                    p = (const char*)Pg_d + (off - 524288);
                pref += *(const volatile float*)p;
            }
        }

        // stage eh_{td} own rows (P.enc) + dh_{td-1} halo (Q.dh)
        for (int v = tid; v < 32*32; v += 512) {
            const int row = v >> 5, seg = v & 31;
            *(bf16x8*)&ehtL[row*264 + seg*8] =
                *(const bf16x8*)&P[(size_t)(grow0 + row)*512 + seg*8];
        }
        for (int v = tid; v < 36*32; v += 512) {
            const int row = v >> 5, seg = v & 31, s = s0 - 2 + row;
            bf16x8 val;
            if ((unsigned)s < 128u)
                val = *(const bf16x8*)&Q[(size_t)(gbatch + s)*512 + 256 + seg*8];
            else {
                #pragma unroll
                for (int i = 0; i < 8; ++i) val[i] = (__bf16)0.f;
            }
            *(bf16x8*)&dhL[row*264 + seg*8] = val;
        }
        asm volatile("" :: "v"(pref));   // keep prefetch loads alive
        __syncthreads();

        // code = sig(eh_{td} @ embW + embb) -> codeL
        {
            f32x4 cacc[2][2];
            #pragma unroll
            for (int m = 0; m < 2; ++m)
                #pragma unroll
                for (int i = 0; i < 2; ++i) cacc[m][i] = f32x4{0.f,0.f,0.f,0.f};
            for (int kt = 0; kt < 8; ++kt) {
                bf16x8 a0 = *(const bf16x8*)&ehtL[(lr)*264      + kt*32 + quad*8];
                bf16x8 a1 = *(const bf16x8*)&ehtL[(16 + lr)*264 + kt*32 + quad*8];
                #pragma unroll
                for (int i = 0; i < 2; ++i) {
                    bf16x8 bf = *(const bf16x8*)&Pemb[((size_t)((2*w + i)*8 + kt)*64 + lane)*8];
                    cacc[0][i] = MFMA(a0, bf, cacc[0][i], 0,0,0);
                    cacc[1][i] = MFMA(a1, bf, cacc[1][i], 0,0,0);
                }
            }
            __syncthreads();   // all ehtL reads done before codeL writes (disjoint anyway)
            #pragma unroll
            for (int i = 0; i < 2; ++i) {
                const int col = (2*w + i)*16 + lr;
                const float bb = embb[col];
                #pragma unroll
                for (int m = 0; m < 2; ++m)
                    #pragma unroll
                    for (int r = 0; r < 4; ++r)
                        codeL[(m*16 + quad*4 + r)*264 + col] = (__bf16)sigf(cacc[m][i][r] + bb);
            }
        }
        __syncthreads();

        // gates acc: code part FIRST (kt 0..7) so codeL dies before kvL overlay
        float bgv[4];
        #pragma unroll
        for (int g = 0; g < 4; ++g) bgv[g] = decbg[g*256 + ch];
        const float ow = outW[ch];

        f32x4 acc[4];
        #pragma unroll
        for (int g = 0; g < 4; ++g) acc[g] = f32x4{0.f,0.f,0.f,0.f};
        for (int kt = 0; kt < 8; ++kt) {
            bf16x8 af = *(const bf16x8*)&codeL[(mt*16 + lr)*264 + kt*32 + quad*8];
            #pragma unroll
            for (int g = 0; g < 4; ++g) {
                const int nt = qt*16 + ct*4 + g;
                bf16x8 bf = *(const bf16x8*)&Pg_d[((size_t)(nt*24 + kt)*64 + lane)*8];
                acc[g] = MFMA(af, bf, acc[g], 0,0,0);
            }
        }
        __syncthreads();   // codeL/ehtL dead; kvL may now overwrite region R

        // dec qkv from dh_{td-1} halo (kvL overlays ehtL+codeL region)
        qkv_lds(dhL, Pqkv_d, qL, kvL, tid);
        __syncthreads();
        attn_lds(qL, kvL, cxL, s0, tid);
        __syncthreads();

        // gates rest (kt 8..23: dhL own | cxL) + LSTM + outproj
        for (int kt = 8; kt < 24; ++kt) {
            const __bf16* As = (kt < 16)
                ? &dhL[(2 + mt*16 + lr)*264 + (kt-8)*32 + quad*8]
                : &cxL[(mt*16 + lr)*264 + (kt-16)*32 + quad*8];
            bf16x8 af = *(const bf16x8*)As;
            #pragma unroll
            for (int g = 0; g < 4; ++g) {
                const int nt = qt*16 + ct*4 + g;
                bf16x8 bf = *(const bf16x8*)&Pg_d[((size_t)(nt*24 + kt)*64 + lane)*8];
                acc[g] = MFMA(af, bf, acc[g], 0,0,0);
            }
        }
        #pragma unroll
        for (int r = 0; r < 4; ++r) {
            const int row = mt*16 + quad*4 + r;
            const float zi = acc[0][r] + bgv[0];
            const float zf = acc[1][r] + bgv[1];
            const float zg = acc[2][r] + bgv[2];
            const float zo = acc[3][r] + bgv[3];
            const float c_old = (float)dhL[(2 + row)*264 + ch];
            const float cn = sigf(zf)*c_old + sigf(zi)*tanhf(zg);
            const float h  = sigf(zo)*tanhf(cn);
            P[(size_t)(grow0 + row)*512 + 256 + ch] = (__bf16)h;
            float pv = h * ow;
            pv += __shfl_xor(pv, 1); pv += __shfl_xor(pv, 2);
            pv += __shfl_xor(pv, 4); pv += __shfl_xor(pv, 8);
            if (lr == 0) outredL[row*4 + ct] = pv;
        }
        __syncthreads();
        if (tid < 32) {
            const float s4 = outredL[tid*4] + outredL[tid*4+1]
                           + outredL[tid*4+2] + outredL[tid*4+3];
            atomicAdd(&outbuf[(size_t)td*Mz + grow0 + tid], s4);
        }
    }
}

// ---------------------------------------------------------------------------
// Final assembly (unchanged, verified)
// ---------------------------------------------------------------------------
__global__ __launch_bounds__(256) void assemble_k(
    const float* __restrict__ outbuf, const float* __restrict__ input,
    const float* __restrict__ outb, float* __restrict__ out)
{
    const int idx = blockIdx.x*256 + threadIdx.x;
    const int NT = NSTEP - TPz;                 // 27
    if (idx >= Bz*NT*Sz) return;
    const int s  = idx & 127;
    const int bi = idx >> 7;
    const int i  = bi % NT;
    const int b  = bi / NT;
    const int t  = i + TPz;
    const float ob = outb[0];
    const float o  = outbuf[t*Mz + (b<<7) + s] + ob;
    const float In = (s == 0)
        ? input[((size_t)(b*Tz + t + 1)*Sz)*3 + 1]
        : outbuf[t*Mz + (b<<7) + s - 1] + ob;
    const float num = input[((size_t)(b*Tz + t)*Sz + s)*3 + 2] + In - o;
    const size_t base = ((size_t)(b*NT + i)*Sz + s)*3;
    out[base+0] = o;
    out[base+1] = In;
    out[base+2] = num;
}

// ---------------------------------------------------------------------------
extern "C" void kernel_launch(void* const* d_in, const int* in_sizes, int n_in,
                              void* d_out, int out_size, void* d_ws, size_t ws_size,
                              hipStream_t stream)
{
    const float* input = (const float*)d_in[0];
    const float* encWq = (const float*)d_in[1];
    const float* encWk = (const float*)d_in[2];
    const float* encWv = (const float*)d_in[3];
    const float* encWg = (const float*)d_in[4];
    const float* encbg = (const float*)d_in[5];
    const float* decWq = (const float*)d_in[6];
    const float* decWk = (const float*)d_in[7];
    const float* decWv = (const float*)d_in[8];
    const float* decWg = (const float*)d_in[9];
    const float* decbg = (const float*)d_in[10];
    const float* embW  = (const float*)d_in[11];
    const float* embb  = (const float*)d_in[12];
    const float* outW  = (const float*)d_in[13];
    const float* outb  = (const float*)d_in[14];

    char* ws = (char*)d_ws;
    size_t off = 0;
    auto alloc = [&](size_t bytes) -> void* {
        void* p = ws + off;
        off += (bytes + 255) & ~(size_t)255;
        return p;
    };
    __bf16* Pqkv_e = (__bf16*)alloc((size_t)768*256*2);
    __bf16* Pqkv_d = (__bf16*)alloc((size_t)768*256*2);
    __bf16* Pemb   = (__bf16*)alloc((size_t)256*256*2);
    __bf16* Pg_e   = (__bf16*)alloc((size_t)1024*512*2);
    __bf16* Pg_d   = (__bf16*)alloc((size_t)1024*768*2);
    __bf16* Xa     = (__bf16*)alloc((size_t)Mz*512*2);   // [ehb|dh] ping
    __bf16* Xb     = (__bf16*)alloc((size_t)Mz*512*2);   // pong
    float*  ec     = (float*) alloc((size_t)Mz*256*4);
    float*  outbuf = (float*) alloc((size_t)NSTEP*Mz*4);

    hipMemsetAsync(Xa, 0, (size_t)Mz*512*2, stream);
    hipMemsetAsync(ec, 0, (size_t)Mz*256*4, stream);
    hipMemsetAsync(outbuf, 0, (size_t)NSTEP*Mz*4, stream);

    prep3<<<6912, 256, 0, stream>>>(encWq, encWk, encWv, encWg,
                                    decWq, decWk, decWv, decWg, embW,
                                    Pqkv_e, Pqkv_d, Pemb, Pg_e, Pg_d);

    for (int k = 0; k <= NSTEP; ++k) {
        __bf16* P = (k & 1) ? Xb : Xa;
        __bf16* Q = (k & 1) ? Xa : Xb;
        step_k<<<512, 512, 0, stream>>>(k, input, P, Q,
                                        Pqkv_e, Pqkv_d, Pemb, Pg_e, Pg_d,
                                        encWg, encbg, decbg, embb, outW,
                                        ec, outbuf);
    }
    assemble_k<<<(Bz*(NSTEP-TPz)*Sz + 255)/256, 256, 0, stream>>>(
        outbuf, input, outb, (float*)d_out);
}

// Round 3
// 1263.834 us; speedup vs baseline: 4.0308x; 1.0736x over previous
//
#include <hip/hip_runtime.h>
#include <hip/hip_bf16.h>

// Problem constants
#define Bz 16
#define Tz 32
#define Sz 128
#define TPz 4
#define Mz (Bz*Sz)          // 2048 rows
#define NSTEP (Tz-1)        // 31

typedef __bf16 bf16x8 __attribute__((ext_vector_type(8)));
typedef float  f32x4  __attribute__((ext_vector_type(4)));

#define MFMA __builtin_amdgcn_mfma_f32_16x16x32_bf16

__device__ __forceinline__ float sigf(float x) { return 1.f/(1.f + __expf(-x)); }

// ---------------------------------------------------------------------------
// prep3 (verified rounds 7/8/10): pack weights (fp32) into bf16 MFMA B-fragment
// order: P[((nt*KT + kt)*64 + lane)*8 + j] =
//        BT[nt*16 + (lane&15)][kt*32 + (lane>>4)*8 + j]
// ---------------------------------------------------------------------------
__global__ __launch_bounds__(256) void prep3(
    const float* __restrict__ encWq, const float* __restrict__ encWk,
    const float* __restrict__ encWv, const float* __restrict__ encWg,
    const float* __restrict__ decWq, const float* __restrict__ decWk,
    const float* __restrict__ decWv, const float* __restrict__ decWg,
    const float* __restrict__ embW,
    __bf16* __restrict__ Pqkv_e, __bf16* __restrict__ Pqkv_d,
    __bf16* __restrict__ Pemb,   __bf16* __restrict__ Pg_e,
    __bf16* __restrict__ Pg_d)
{
    int id = blockIdx.x * 256 + threadIdx.x;
    if (id < 768*256) {
        int f = id >> 9, e = id & 511, l = e >> 3, j = e & 7;
        int nt = f >> 3, kt = f & 7;
        int n = nt*16 + (l & 15), k = kt*32 + (l >> 4)*8 + j;
        float v = (n < 256) ? encWq[k*256 + n]
                : (n < 512) ? encWk[k*256 + (n-256)]
                            : encWv[k*256 + (n-512)];
        Pqkv_e[id] = (__bf16)v; return;
    }
    id -= 768*256;
    if (id < 768*256) {
        int f = id >> 9, e = id & 511, l = e >> 3, j = e & 7;
        int nt = f >> 3, kt = f & 7;
        int n = nt*16 + (l & 15), k = kt*32 + (l >> 4)*8 + j;
        float v = (n < 256) ? decWq[k*256 + n]
                : (n < 512) ? decWk[k*256 + (n-256)]
                            : decWv[k*256 + (n-512)];
        Pqkv_d[id] = (__bf16)v; return;
    }
    id -= 768*256;
    if (id < 256*256) {
        int f = id >> 9, e = id & 511, l = e >> 3, j = e & 7;
        int nt = f >> 3, kt = f & 7;
        int n = nt*16 + (l & 15), k = kt*32 + (l >> 4)*8 + j;
        Pemb[id] = (__bf16)embW[k*256 + n]; return;
    }
    id -= 256*256;
    if (id < 1024*512) {
        int f = id >> 9, e = id & 511, l = e >> 3, j = e & 7;
        int nt = f >> 4, kt = f & 15;
        int cht = nt >> 2, g = nt & 3;
        int ch = cht*16 + (l & 15), k = kt*32 + (l >> 4)*8 + j;
        Pg_e[id] = (__bf16)encWg[(size_t)(3 + k)*1024 + g*256 + ch]; return;
    }
    id -= 1024*512;
    if (id < 1024*768) {
        int f = id >> 9, e = id & 511, l = e >> 3, j = e & 7;
        int nt = f / 24, kt = f % 24;
        int cht = nt >> 2, g = nt & 3;
        int ch = cht*16 + (l & 15), k = kt*32 + (l >> 4)*8 + j;
        Pg_d[id] = (__bf16)decWg[(size_t)k*1024 + g*256 + ch]; return;
    }
}

// ---------------------------------------------------------------------------
// qkv GEMM from 36-row staged state (stride 264) -> qL (own 32 rows), kvL (36).
// (verified rounds 7/8/10)  NEW: 2-kt register-staged pipeline — all loads of
// a chunk issue before its MFMAs (MFMA order unchanged: kt asc, acc order same).
// ---------------------------------------------------------------------------
__device__ __forceinline__ void qkv_lds(
    const __bf16* src264, const __bf16* __restrict__ P,
    __bf16* qL, __bf16* kvL, int tid)
{
    const int w = tid >> 6, lane = tid & 63, quad = (lane >> 4), lr = lane & 15;
    #pragma unroll
    for (int ng = 0; ng < 3; ++ng) {
        const int ntA = w*6 + ng*2;
        f32x4 acc[2][3];
        #pragma unroll
        for (int i = 0; i < 2; ++i)
            #pragma unroll
            for (int m = 0; m < 3; ++m) acc[i][m] = f32x4{0.f,0.f,0.f,0.f};
        #pragma unroll
        for (int kc = 0; kc < 8; kc += 2) {
            bf16x8 a[2][3], b[2][2];
            #pragma unroll
            for (int u = 0; u < 2; ++u) {
                const int kt = kc + u;
                a[u][0] = *(const bf16x8*)&src264[(lr)*264      + kt*32 + quad*8];
                a[u][1] = *(const bf16x8*)&src264[(16 + lr)*264 + kt*32 + quad*8];
                a[u][2] = *(const bf16x8*)&src264[(32 + lr)*264 + kt*32 + quad*8];
                b[u][0] = *(const bf16x8*)&P[((size_t)(ntA*8 + kt)*64 + lane)*8];
                b[u][1] = *(const bf16x8*)&P[((size_t)((ntA+1)*8 + kt)*64 + lane)*8];
            }
            #pragma unroll
            for (int u = 0; u < 2; ++u) {
                acc[0][0] = MFMA(a[u][0], b[u][0], acc[0][0], 0,0,0);
                acc[0][1] = MFMA(a[u][1], b[u][0], acc[0][1], 0,0,0);
                acc[0][2] = MFMA(a[u][2], b[u][0], acc[0][2], 0,0,0);
                acc[1][0] = MFMA(a[u][0], b[u][1], acc[1][0], 0,0,0);
                acc[1][1] = MFMA(a[u][1], b[u][1], acc[1][1], 0,0,0);
                acc[1][2] = MFMA(a[u][2], b[u][1], acc[1][2], 0,0,0);
            }
        }
        #pragma unroll
        for (int i = 0; i < 2; ++i) {
            const int col = (ntA + i)*16 + lr;
            #pragma unroll
            for (int m = 0; m < 3; ++m)
                #pragma unroll
                for (int r = 0; r < 4; ++r) {
                    const int row = m*16 + quad*4 + r;
                    const float v = acc[i][m][r];
                    if (col < 256) {
                        if (row >= 2 && row < 34) qL[(row-2)*264 + col] = (__bf16)v;
                    } else if (row < 36) {
                        kvL[row*520 + (col - 256)] = (__bf16)v;
                    }
                }
        }
    }
}

// ---------------------------------------------------------------------------
// Attention (32 rows) from LDS qL/kvL -> cxL. (verified rounds 7/8/10)
// cxL MAY alias qL: each lane reads only the q chunk it later overwrites.
// ---------------------------------------------------------------------------
__device__ __forceinline__ void attn_lds(
    const __bf16* qL, const __bf16* kvL, __bf16* cxL, int s0, int tid)
{
    const int w = tid >> 6, lane = tid & 63, quad = lane >> 4, lr = lane & 15;
    const int r = 4*w + quad, s = s0 + r, ch0 = lr*16;

    float q[16];
    {
        bf16x8 q0 = *(const bf16x8*)&qL[r*264 + ch0];
        bf16x8 q1 = *(const bf16x8*)&qL[r*264 + ch0 + 8];
        #pragma unroll
        for (int i = 0; i < 8; ++i) { q[i] = (float)q0[i]; q[8+i] = (float)q1[i]; }
    }
    bf16x8 zv;
    #pragma unroll
    for (int i = 0; i < 8; ++i) zv[i] = (__bf16)0.f;

    const int offs[4] = {2, 1, -1, -2};
    float sc[4]; bf16x8 v0[4], v1[4];
    #pragma unroll
    for (int n = 0; n < 4; ++n) {
        const int s2 = s + offs[n];
        const bool ok = ((unsigned)s2 < 128u);
        const int lrow = r + offs[n] + 2;
        float p = 0.f;
        if (ok) {
            bf16x8 k0 = *(const bf16x8*)&kvL[lrow*520 + ch0];
            bf16x8 k1 = *(const bf16x8*)&kvL[lrow*520 + ch0 + 8];
            v0[n] = *(const bf16x8*)&kvL[lrow*520 + 256 + ch0];
            v1[n] = *(const bf16x8*)&kvL[lrow*520 + 256 + ch0 + 8];
            #pragma unroll
            for (int i = 0; i < 8; ++i) p += q[i]*(float)k0[i] + q[8+i]*(float)k1[i];
        } else { v0[n] = zv; v1[n] = zv; }
        p += __shfl_xor(p, 1);
        sc[n] = ok ? p * 0.17677669529663687f : 0.f;
    }
    const float mx = fmaxf(fmaxf(sc[0], sc[1]), fmaxf(sc[2], sc[3]));
    float se = 0.f, aw[4];
    #pragma unroll
    for (int n = 0; n < 4; ++n) { aw[n] = __expf(sc[n] - mx); se += aw[n]; }
    const float inv = 1.f / se;
    float cx[16];
    #pragma unroll
    for (int i = 0; i < 16; ++i) cx[i] = 0.f;
    #pragma unroll
    for (int n = 0; n < 4; ++n)
        #pragma unroll
        for (int i = 0; i < 8; ++i) {
            cx[i]   += aw[n]*(float)v0[n][i];
            cx[8+i] += aw[n]*(float)v1[n][i];
        }
    bf16x8 o0, o1;
    #pragma unroll
    for (int i = 0; i < 8; ++i) { o0[i] = (__bf16)(cx[i]*inv); o1[i] = (__bf16)(cx[8+i]*inv); }
    *(bf16x8*)&cxL[r*264 + ch0]     = o0;
    *(bf16x8*)&cxL[r*264 + ch0 + 8] = o1;
}

// ---------------------------------------------------------------------------
// step_k: ONE dispatch per scan step k (k = 0..NSTEP).
// blocks 0..255  : dec step td = k-1 (skip if k==0)
// blocks 256..511: enc step te = k   (skip if k==NSTEP)
//
// Round-2 post-mortem: L2 warm-up prefetch was net-negative (FETCH +12MB/step,
// dur +2us) -> reverted. VGPR_Count=64 showed the compiler serializing the
// weight-fragment load chains. This round: explicit register-staged chunks
// (4-kt for gates/code, 2-kt for qkv) raise loads-in-flight ~4x within the
// free 128-VGPR budget (LDS pins occupancy at 2 blocks/CU either way), plus
// hoisted ec/bias/outW scalar loads so their latency overlaps staging.
// MFMA accumulation order is unchanged everywhere.
// ---------------------------------------------------------------------------
#define SM_A264   0
#define SM_R      19008
#define SM_CODE   35904
#define SM_Q      56448
#define SM_MISC   73344
#define SM_TOTAL  73856

__global__ __launch_bounds__(512, 4) void step_k(
    int k, const float* __restrict__ input,
    __bf16* __restrict__ P, __bf16* __restrict__ Q,
    const __bf16* __restrict__ Pqkv_e, const __bf16* __restrict__ Pqkv_d,
    const __bf16* __restrict__ Pemb,   const __bf16* __restrict__ Pg_e,
    const __bf16* __restrict__ Pg_d,
    const float* __restrict__ encWg, const float* __restrict__ encbg,
    const float* __restrict__ decbg, const float* __restrict__ embb,
    const float* __restrict__ outW,
    float* __restrict__ ec, float* __restrict__ outbuf)
{
    __shared__ __attribute__((aligned(16))) char SM[SM_TOTAL];

    const int tid  = threadIdx.x;
    const int w    = tid >> 6;
    const int lane = tid & 63;
    const int quad = lane >> 4, lr = lane & 15;
    const int mt = w >> 2, ct = w & 3;

    __bf16* aL  = (__bf16*)(SM + SM_A264);   // hL / dhL
    __bf16* kvL = (__bf16*)(SM + SM_R);
    __bf16* qL  = (__bf16*)(SM + SM_Q);
    __bf16* cxL = qL;                        // alias (safe, see attn_lds)

    if (blockIdx.x >= 256) {
        // ===================== ENC body (step te = k) =====================
        if (k >= NSTEP) return;
        const int bid = blockIdx.x - 256;
        const int b = bid >> 4, rg = (bid >> 2) & 3, qt = bid & 3;
        const int gbatch = b*128, s0 = rg*32, grow0 = gbatch + s0;
        const int ch = qt*64 + ct*16 + lr;
        float* xL = (float*)(SM + SM_MISC);

        // hoisted scalar loads: latency overlaps staging + qkv + attn
        float wx0[4], wx1[4], wx2[4], bgv[4], ecv[4];
        #pragma unroll
        for (int g = 0; g < 4; ++g) {
            const int c = g*256 + ch;
            wx0[g] = encWg[c]; wx1[g] = encWg[1024 + c]; wx2[g] = encWg[2048 + c];
            bgv[g] = encbg[c];
        }
        #pragma unroll
        for (int r = 0; r < 4; ++r)   // safe early read: only this thread writes it
            ecv[r] = ec[(size_t)(grow0 + mt*16 + quad*4 + r)*256 + ch];

        // stage eh_{k-1} halo rows (s0-2 .. s0+33) from P.enc
        for (int v = tid; v < 36*32; v += 512) {
            const int row = v >> 5, seg = v & 31, s = s0 - 2 + row;
            bf16x8 val;
            if ((unsigned)s < 128u)
                val = *(const bf16x8*)&P[(size_t)(gbatch + s)*512 + seg*8];
            else {
                #pragma unroll
                for (int i = 0; i < 8; ++i) val[i] = (__bf16)0.f;
            }
            *(bf16x8*)&aL[row*264 + seg*8] = val;
        }
        if (tid < 96) xL[tid] = input[((size_t)(b*Tz + k)*Sz + s0)*3 + tid];
        __syncthreads();

        qkv_lds(aL, Pqkv_e, qL, kvL, tid);
        __syncthreads();
        attn_lds(qL, kvL, cxL, s0, tid);
        __syncthreads();

        // gates (K=512: aL own rows | cxL) + LSTM  — 4-kt register-staged chunks
        f32x4 acc[4];
        #pragma unroll
        for (int g = 0; g < 4; ++g) acc[g] = f32x4{0.f,0.f,0.f,0.f};
        #pragma unroll
        for (int kc = 0; kc < 16; kc += 4) {
            bf16x8 a4[4], b4[4][4];
            #pragma unroll
            for (int u = 0; u < 4; ++u) {
                const int kt = kc + u;
                const __bf16* As = (kt < 8)
                    ? &aL [(2 + mt*16 + lr)*264 + kt*32 + quad*8]
                    : &cxL[(mt*16 + lr)*264 + (kt-8)*32 + quad*8];
                a4[u] = *(const bf16x8*)As;
                #pragma unroll
                for (int g = 0; g < 4; ++g) {
                    const int nt = qt*16 + ct*4 + g;
                    b4[u][g] = *(const bf16x8*)&Pg_e[((size_t)(nt*16 + kt)*64 + lane)*8];
                }
            }
            #pragma unroll
            for (int u = 0; u < 4; ++u)
                #pragma unroll
                for (int g = 0; g < 4; ++g)
                    acc[g] = MFMA(a4[u], b4[u][g], acc[g], 0,0,0);
        }
        #pragma unroll
        for (int r = 0; r < 4; ++r) {
            const int row = mt*16 + quad*4 + r;
            const float x0 = xL[row*3], x1 = xL[row*3+1], x2 = xL[row*3+2];
            const float zi = acc[0][r] + x0*wx0[0] + x1*wx1[0] + x2*wx2[0] + bgv[0];
            const float zf = acc[1][r] + x0*wx0[1] + x1*wx1[1] + x2*wx2[1] + bgv[1];
            const float zg = acc[2][r] + x0*wx0[2] + x1*wx1[2] + x2*wx2[2] + bgv[2];
            const float zo = acc[3][r] + x0*wx0[3] + x1*wx1[3] + x2*wx2[3] + bgv[3];
            const size_t ei = (size_t)(grow0 + row)*256 + ch;
            const float cn = sigf(zf)*ecv[r] + sigf(zi)*tanhf(zg);
            ec[ei] = cn;
            Q[(size_t)(grow0 + row)*512 + ch] = (__bf16)(sigf(zo)*tanhf(cn));
        }
    } else {
        // ===================== DEC body (step td = k-1) =====================
        if (k < 1) return;
        const int td = k - 1;
        const int bid = blockIdx.x;
        const int b = bid >> 4, rg = (bid >> 2) & 3, qt = bid & 3;
        const int gbatch = b*128, s0 = rg*32, grow0 = gbatch + s0;
        const int ch = qt*64 + ct*16 + lr;
        __bf16* dhL   = aL;
        __bf16* ehtL  = (__bf16*)(SM + SM_R);      // dead after code GEMM
        __bf16* codeL = (__bf16*)(SM + SM_CODE);   // dead after gates code-part
        float* outredL = (float*)(SM + SM_MISC);

        // hoisted scalar loads
        float bgv[4];
        #pragma unroll
        for (int g = 0; g < 4; ++g) bgv[g] = decbg[g*256 + ch];
        const float ow  = outW[ch];
        const float bb0 = embb[(2*w + 0)*16 + lr];
        const float bb1 = embb[(2*w + 1)*16 + lr];

        // stage eh_{td} own rows (P.enc) + dh_{td-1} halo (Q.dh)
        for (int v = tid; v < 32*32; v += 512) {
            const int row = v >> 5, seg = v & 31;
            *(bf16x8*)&ehtL[row*264 + seg*8] =
                *(const bf16x8*)&P[(size_t)(grow0 + row)*512 + seg*8];
        }
        for (int v = tid; v < 36*32; v += 512) {
            const int row = v >> 5, seg = v & 31, s = s0 - 2 + row;
            bf16x8 val;
            if ((unsigned)s < 128u)
                val = *(const bf16x8*)&Q[(size_t)(gbatch + s)*512 + 256 + seg*8];
            else {
                #pragma unroll
                for (int i = 0; i < 8; ++i) val[i] = (__bf16)0.f;
            }
            *(bf16x8*)&dhL[row*264 + seg*8] = val;
        }
        __syncthreads();

        // code = sig(eh_{td} @ embW + embb) -> codeL  (4-kt chunks)
        {
            f32x4 cacc[2][2];
            #pragma unroll
            for (int m = 0; m < 2; ++m)
                #pragma unroll
                for (int i = 0; i < 2; ++i) cacc[m][i] = f32x4{0.f,0.f,0.f,0.f};
            #pragma unroll
            for (int kc = 0; kc < 8; kc += 4) {
                bf16x8 a0s[4], a1s[4], bs[4][2];
                #pragma unroll
                for (int u = 0; u < 4; ++u) {
                    const int kt = kc + u;
                    a0s[u] = *(const bf16x8*)&ehtL[(lr)*264      + kt*32 + quad*8];
                    a1s[u] = *(const bf16x8*)&ehtL[(16 + lr)*264 + kt*32 + quad*8];
                    #pragma unroll
                    for (int i = 0; i < 2; ++i)
                        bs[u][i] = *(const bf16x8*)&Pemb[((size_t)((2*w + i)*8 + kt)*64 + lane)*8];
                }
                #pragma unroll
                for (int u = 0; u < 4; ++u)
                    #pragma unroll
                    for (int i = 0; i < 2; ++i) {
                        cacc[0][i] = MFMA(a0s[u], bs[u][i], cacc[0][i], 0,0,0);
                        cacc[1][i] = MFMA(a1s[u], bs[u][i], cacc[1][i], 0,0,0);
                    }
            }
            // (removed redundant barrier: ehtL reads vs codeL writes are
            //  disjoint LDS regions; cross-wave codeL reads are gated by the
            //  barrier below)
            #pragma unroll
            for (int i = 0; i < 2; ++i) {
                const int col = (2*w + i)*16 + lr;
                const float bb = (i == 0) ? bb0 : bb1;
                #pragma unroll
                for (int m = 0; m < 2; ++m)
                    #pragma unroll
                    for (int r = 0; r < 4; ++r)
                        codeL[(m*16 + quad*4 + r)*264 + col] = (__bf16)sigf(cacc[m][i][r] + bb);
            }
        }
        __syncthreads();

        // gates acc: code part FIRST (kt 0..7) so codeL dies before kvL overlay
        f32x4 acc[4];
        #pragma unroll
        for (int g = 0; g < 4; ++g) acc[g] = f32x4{0.f,0.f,0.f,0.f};
        #pragma unroll
        for (int kc = 0; kc < 8; kc += 4) {
            bf16x8 a4[4], b4[4][4];
            #pragma unroll
            for (int u = 0; u < 4; ++u) {
                const int kt = kc + u;
                a4[u] = *(const bf16x8*)&codeL[(mt*16 + lr)*264 + kt*32 + quad*8];
                #pragma unroll
                for (int g = 0; g < 4; ++g) {
                    const int nt = qt*16 + ct*4 + g;
                    b4[u][g] = *(const bf16x8*)&Pg_d[((size_t)(nt*24 + kt)*64 + lane)*8];
                }
            }
            #pragma unroll
            for (int u = 0; u < 4; ++u)
                #pragma unroll
                for (int g = 0; g < 4; ++g)
                    acc[g] = MFMA(a4[u], b4[u][g], acc[g], 0,0,0);
        }
        __syncthreads();   // codeL/ehtL dead; kvL may now overwrite region R

        // dec qkv from dh_{td-1} halo (kvL overlays ehtL+codeL region)
        qkv_lds(dhL, Pqkv_d, qL, kvL, tid);
        __syncthreads();
        attn_lds(qL, kvL, cxL, s0, tid);
        __syncthreads();

        // gates rest (kt 8..23: dhL own | cxL) + LSTM + outproj  (4-kt chunks)
        #pragma unroll
        for (int kc = 8; kc < 24; kc += 4) {
            bf16x8 a4[4], b4[4][4];
            #pragma unroll
            for (int u = 0; u < 4; ++u) {
                const int kt = kc + u;
                const __bf16* As = (kt < 16)
                    ? &dhL[(2 + mt*16 + lr)*264 + (kt-8)*32 + quad*8]
                    : &cxL[(mt*16 + lr)*264 + (kt-16)*32 + quad*8];
                a4[u] = *(const bf16x8*)As;
                #pragma unroll
                for (int g = 0; g < 4; ++g) {
                    const int nt = qt*16 + ct*4 + g;
                    b4[u][g] = *(const bf16x8*)&Pg_d[((size_t)(nt*24 + kt)*64 + lane)*8];
                }
            }
            #pragma unroll
            for (int u = 0; u < 4; ++u)
                #pragma unroll
                for (int g = 0; g < 4; ++g)
                    acc[g] = MFMA(a4[u], b4[u][g], acc[g], 0,0,0);
        }
        #pragma unroll
        for (int r = 0; r < 4; ++r) {
            const int row = mt*16 + quad*4 + r;
            const float zi = acc[0][r] + bgv[0];
            const float zf = acc[1][r] + bgv[1];
            const float zg = acc[2][r] + bgv[2];
            const float zo = acc[3][r] + bgv[3];
            const float c_old = (float)dhL[(2 + row)*264 + ch];
            const float cn = sigf(zf)*c_old + sigf(zi)*tanhf(zg);
            const float h  = sigf(zo)*tanhf(cn);
            P[(size_t)(grow0 + row)*512 + 256 + ch] = (__bf16)h;
            float pv = h * ow;
            pv += __shfl_xor(pv, 1); pv += __shfl_xor(pv, 2);
            pv += __shfl_xor(pv, 4); pv += __shfl_xor(pv, 8);
            if (lr == 0) outredL[row*4 + ct] = pv;
        }
        __syncthreads();
        if (tid < 32) {
            const float s4 = outredL[tid*4] + outredL[tid*4+1]
                           + outredL[tid*4+2] + outredL[tid*4+3];
            atomicAdd(&outbuf[(size_t)td*Mz + grow0 + tid], s4);
        }
    }
}

// ---------------------------------------------------------------------------
// Final assembly (unchanged, verified)
// ---------------------------------------------------------------------------
__global__ __launch_bounds__(256) void assemble_k(
    const float* __restrict__ outbuf, const float* __restrict__ input,
    const float* __restrict__ outb, float* __restrict__ out)
{
    const int idx = blockIdx.x*256 + threadIdx.x;
    const int NT = NSTEP - TPz;                 // 27
    if (idx >= Bz*NT*Sz) return;
    const int s  = idx & 127;
    const int bi = idx >> 7;
    const int i  = bi % NT;
    const int b  = bi / NT;
    const int t  = i + TPz;
    const float ob = outb[0];
    const float o  = outbuf[t*Mz + (b<<7) + s] + ob;
    const float In = (s == 0)
        ? input[((size_t)(b*Tz + t + 1)*Sz)*3 + 1]
        : outbuf[t*Mz + (b<<7) + s - 1] + ob;
    const float num = input[((size_t)(b*Tz + t)*Sz + s)*3 + 2] + In - o;
    const size_t base = ((size_t)(b*NT + i)*Sz + s)*3;
    out[base+0] = o;
    out[base+1] = In;
    out[base+2] = num;
}

// ---------------------------------------------------------------------------
extern "C" void kernel_launch(void* const* d_in, const int* in_sizes, int n_in,
                              void* d_out, int out_size, void* d_ws, size_t ws_size,
                              hipStream_t stream)
{
    const float* input = (const float*)d_in[0];
    const float* encWq = (const float*)d_in[1];
    const float* encWk = (const float*)d_in[2];
    const float* encWv = (const float*)d_in[3];
    const float* encWg = (const float*)d_in[4];
    const float* encbg = (const float*)d_in[5];
    const float* decWq = (const float*)d_in[6];
    const float* decWk = (const float*)d_in[7];
    const float* decWv = (const float*)d_in[8];
    const float* decWg = (const float*)d_in[9];
    const float* decbg = (const float*)d_in[10];
    const float* embW  = (const float*)d_in[11];
    const float* embb  = (const float*)d_in[12];
    const float* outW  = (const float*)d_in[13];
    const float* outb  = (const float*)d_in[14];

    char* ws = (char*)d_ws;
    size_t off = 0;
    auto alloc = [&](size_t bytes) -> void* {
        void* p = ws + off;
        off += (bytes + 255) & ~(size_t)255;
        return p;
    };
    __bf16* Pqkv_e = (__bf16*)alloc((size_t)768*256*2);
    __bf16* Pqkv_d = (__bf16*)alloc((size_t)768*256*2);
    __bf16* Pemb   = (__bf16*)alloc((size_t)256*256*2);
    __bf16* Pg_e   = (__bf16*)alloc((size_t)1024*512*2);
    __bf16* Pg_d   = (__bf16*)alloc((size_t)1024*768*2);
    __bf16* Xa     = (__bf16*)alloc((size_t)Mz*512*2);   // [ehb|dh] ping
    __bf16* Xb     = (__bf16*)alloc((size_t)Mz*512*2);   // pong
    float*  ec     = (float*) alloc((size_t)Mz*256*4);
    float*  outbuf = (float*) alloc((size_t)NSTEP*Mz*4);

    hipMemsetAsync(Xa, 0, (size_t)Mz*512*2, stream);
    hipMemsetAsync(ec, 0, (size_t)Mz*256*4, stream);
    hipMemsetAsync(outbuf, 0, (size_t)NSTEP*Mz*4, stream);

    prep3<<<6912, 256, 0, stream>>>(encWq, encWk, encWv, encWg,
                                    decWq, decWk, decWv, decWg, embW,
                                    Pqkv_e, Pqkv_d, Pemb, Pg_e, Pg_d);

    for (int k = 0; k <= NSTEP; ++k) {
        __bf16* P = (k & 1) ? Xb : Xa;
        __bf16* Q = (k & 1) ? Xa : Xb;
        step_k<<<512, 512, 0, stream>>>(k, input, P, Q,
                                        Pqkv_e, Pqkv_d, Pemb, Pg_e, Pg_d,
                                        encWg, encbg, decbg, embb, outW,
                                        ec, outbuf);
    }
    assemble_k<<<(Bz*(NSTEP-TPz)*Sz + 255)/256, 256, 0, stream>>>(
        outbuf, input, outb, (float*)d_out);
}